// Round 10
// baseline (161.710 us; speedup 1.0000x reference)
//
#include <hip/hip_runtime.h>

// EdgeAttention round 10: grid-size / co-residency fix for the fused scale-0 kernel.
//  r9 finding: 400-block grid = <2 blocks/CU -> zero inter-block overlap of the DMA
//  drain (m102: efficiency ~ grid size; m97 relies on ~3 blocks/CU implicit overlap).
//  proj0_dots v3: 4x16-px tiles (64-B coalesced F rows) -> 800 blocks x 256 thr,
//  single-buffered m97-style loop (DMA -> barrier -> compute), 24.6 KB LDS -> ~4
//  blocks/CU co-resident. Coarse ownership per tile: 16 u1 px, 4 u2 px (d23), fine px
//  (d01/d02/d03), d12/d13 per owned u1 px; u3 is data-only. proj_small (+W0 pack) and
//  softmax unchanged (validated). Harness fixed cost measured at ~95 us (256 MiB ws
//  poison fill = 41 us @6.5 TB/s + input restores) — not controllable.

#define CCH 256
#define WPITCH 40   // proj_small LDS pitch (validated)

typedef __attribute__((ext_vector_type(8))) short short8;
typedef __attribute__((ext_vector_type(4))) short short4_;
typedef __attribute__((ext_vector_type(4))) float float4_;

__device__ inline short f2bf(float x) {
    union { float f; unsigned u; } c; c.f = x;
    unsigned u = c.u + 0x7FFFu + ((c.u >> 16) & 1u);
    return (short)(u >> 16);
}
__device__ inline float bf2f(short b) {
    union { unsigned u; float f; } c; c.u = ((unsigned)(unsigned short)b) << 16;
    return c.f;
}

__device__ inline void dma16(const void* g, void* l) {
    __builtin_amdgcn_global_load_lds(
        (const __attribute__((address_space(1))) void*)g,
        (__attribute__((address_space(3))) void*)l, 16, 0, 0);
}

// ---------- proj_small: scales 1..3 -> pixel-major unit vectors (validated r8/r9) ----
// Blocks 272..303 pack W0 fp32 -> bf16 fragment-linear for proj0_dots' DMA.
__global__ __launch_bounds__(256) void proj_small(
    const float* __restrict__ f1, const float* __restrict__ f2,
    const float* __restrict__ f3,
    const float* __restrict__ w0, const float* __restrict__ w1,
    const float* __restrict__ w2, const float* __restrict__ w3,
    const float* __restrict__ b1, const float* __restrict__ b2,
    const float* __restrict__ b3,
    short* __restrict__ u1, short* __restrict__ u2, short* __restrict__ u3,
    short* __restrict__ wp)
{
    __shared__ __align__(16) short Wt[256 * WPITCH];
    __shared__ __align__(16) short Ft[64 * WPITCH];

    const int blk = blockIdx.x;
    const int t = threadIdx.x;

    if (blk >= 272) {   // W0 pack: pos = ks*8192 + mt*512 + (quad*16+ln)*8 + e
        int id = (blk - 272) * 256 + t;
        int ks = id >> 10;
        int rest = id & 1023;
        int mt = rest >> 6;
        int fl = rest & 63;
        int ln = fl & 15, qd = fl >> 4;
        const float* src = w0 + (size_t)(mt * 16 + ln) * CCH + ks * 32 + qd * 8;
        short8 v;
#pragma unroll
        for (int j = 0; j < 8; ++j) v[j] = f2bf(src[j]);
        *(short8*)(wp + (size_t)id * 8) = v;
        return;
    }

    int b, tile, L;
    const float* F; const float* Wg; const float* bias; short* U;
    if (blk < 200)      { int r = blk;       b = r / 25; tile = r % 25; L = 1600; F = f1; Wg = w1; bias = b1; U = u1; }
    else if (blk < 256) { int r = blk - 200; b = r / 7;  tile = r % 7;  L = 400;  F = f2; Wg = w2; bias = b2; U = u2; }
    else                { int r = blk - 256; b = r / 2;  tile = r % 2;  L = 100;  F = f3; Wg = w3; bias = b3; U = u3; }

    const int lane = t & 63;
    const int wav  = t >> 6;
    const int ln   = lane & 15;
    const int quad = lane >> 4;
    const int pixbase = tile * 64;
    const float* Fb = F + (size_t)b * CCH * L;

    const int wo = t >> 2;
    const int wk = (t & 3) * 8;
    const int fpix = t & 63;
    const int fchunk = t >> 6;
    const int gpix0 = pixbase + fpix;
    const bool pin = gpix0 < L;
    const int gl0 = pin ? gpix0 : 0;

    float4_ wbufA[4], wbufB[4];
    float fbuf[8];
    auto loadW = [&](int ks) {
#pragma unroll
        for (int p = 0; p < 4; ++p) {
            const float* srcp = Wg + (size_t)(p * 64 + wo) * CCH + ks * 32 + wk;
            wbufA[p] = *(const float4_*)srcp;
            wbufB[p] = *(const float4_*)(srcp + 4);
        }
    };
    auto loadF = [&](int ks) {
        const float* fs = Fb + (size_t)(ks * 32 + fchunk * 8) * L + gl0;
#pragma unroll
        for (int j = 0; j < 8; ++j) fbuf[j] = fs[(size_t)j * L];
    };

    float4_ acc[16];
#pragma unroll
    for (int i = 0; i < 16; ++i) acc[i] = (float4_){0.f, 0.f, 0.f, 0.f};

    loadW(0); loadF(0);
    for (int ks = 0; ks < 8; ++ks) {
        __syncthreads();
#pragma unroll
        for (int p = 0; p < 4; ++p) {
            short8 v;
#pragma unroll
            for (int e = 0; e < 4; ++e) { v[e] = f2bf(wbufA[p][e]); v[e + 4] = f2bf(wbufB[p][e]); }
            *(short8*)(&Wt[(p * 64 + wo) * WPITCH + wk]) = v;
        }
        {
            short8 v;
#pragma unroll
            for (int j = 0; j < 8; ++j) v[j] = pin ? f2bf(fbuf[j]) : (short)0;
            *(short8*)(&Ft[fpix * WPITCH + fchunk * 8]) = v;
        }
        __syncthreads();
        const int ksn = (ks + 1) & 7;
        loadW(ksn); loadF(ksn);

        short8 bfrag = *(const short8*)(&Ft[(wav * 16 + ln) * WPITCH + quad * 8]);
#pragma unroll
        for (int mt = 0; mt < 16; ++mt) {
            short8 afrag = *(const short8*)(&Wt[(mt * 16 + ln) * WPITCH + quad * 8]);
            acc[mt] = __builtin_amdgcn_mfma_f32_16x16x32_bf16(afrag, bfrag, acc[mt], 0, 0, 0);
        }
    }

    float ss = 0.f;
#pragma unroll
    for (int mt = 0; mt < 16; ++mt) {
        float4_ bv = *(const float4_*)(bias + mt * 16 + quad * 4);
#pragma unroll
        for (int r = 0; r < 4; ++r) { float v = acc[mt][r] + bv[r]; acc[mt][r] = v; ss += v * v; }
    }
    ss += __shfl_xor(ss, 16);
    ss += __shfl_xor(ss, 32);
    const float inv = 1.f / sqrtf(fmaxf(ss, 1e-24f));

    const int gpixw = pixbase + wav * 16 + ln;
    if (gpixw < L) {
        short* dst = U + ((size_t)b * L + gpixw) * CCH;
#pragma unroll
        for (int mt = 0; mt < 16; ++mt) {
            short4_ v;
#pragma unroll
            for (int r = 0; r < 4; ++r) v[r] = f2bf(acc[mt][r] * inv);
            *(short4_*)(dst + mt * 16 + quad * 4) = v;
        }
    }
}

// ---------- proj0_dots v3: 4x16-px tiles, 800 blocks, single-buffer DMA loop ----------
// Block = (cell = blockIdx.x 0..99 -> band RB = c/5 (0..19), colgrp CB = c%5; b =
// blockIdx.y). Fine px: rows [4RB,4RB+4), cols [16CB,16CB+16). 4 waves, wave w owns
// px [16w, 16w+16).
__global__ __launch_bounds__(256) void proj0_dots(
    const float* __restrict__ F, const short* __restrict__ wp,
    const float* __restrict__ bias,
    const short* __restrict__ u1, const short* __restrict__ u2,
    const short* __restrict__ u3,
    float* __restrict__ partial)
{
    __shared__ __align__(16) char smem[24576 + 256];
    short* Wb = (short*)smem;                    // 16 KB bf16 W slice (fragment-linear)
    float* Fb = (float*)(smem + 16384);          //  8 KB fp32 F slice [32 ch][64 px]
    // Epilogue aliases (after post-loop barrier):
    short* S1 = (short*)smem;                    // 16 px * 256 ch bf16 = 8192 B
    short* S2 = (short*)(smem + 8192);           //  4 px = 2048 B
    short* S3 = (short*)(smem + 10240);          //  2 px = 1024 B
    float* redF = (float*)(smem + 11264);        // [4][3]
    float* redC = (float*)(smem + 11264 + 48);   // [3]

    const int c  = blockIdx.x;
    const int b  = blockIdx.y;
    const int RB = c / 5, CB = c - RB * 5;
    const int t  = threadIdx.x;
    const int lane = t & 63;
    const int wav  = t >> 6;           // 0..3
    const int ln   = lane & 15;
    const int quad = lane >> 4;
    const float* Fbase = F + (size_t)b * CCH * 6400;

    auto dmaW = [&](int ks) {
#pragma unroll
        for (int m = 0; m < 4; ++m) {
            const int k = wav * 4 + m;                      // 0..15
            dma16(wp + (size_t)ks * 8192 + k * 512 + lane * 8, Wb + k * 512);
        }
    };
    auto dmaF = [&](int ks) {
#pragma unroll
        for (int m = 0; m < 2; ++m) {
            const int k = wav * 2 + m;                      // 0..7 -> ch 4k..4k+3
            const int ch = k * 4 + (lane >> 4);
            const int px4 = (lane & 15) * 4;                // 4 px per lane
            const int gpx = (4 * RB + (px4 >> 4)) * 80 + 16 * CB + (px4 & 15);
            dma16(Fbase + (size_t)(ks * 32 + ch) * 6400 + gpx, Fb + k * 256);
        }
    };

    float4_ acc[16];
#pragma unroll
    for (int i = 0; i < 16; ++i) acc[i] = (float4_){0.f, 0.f, 0.f, 0.f};

    const int pxme = wav * 16 + ln;    // 0..63

    for (int ks = 0; ks < 8; ++ks) {
        __syncthreads();               // previous compute's LDS reads done
        dmaW(ks); dmaF(ks);
        __syncthreads();               // vmcnt(0) drain before barrier -> DMA complete
        short8 bfrag;
#pragma unroll
        for (int j = 0; j < 8; ++j)
            bfrag[j] = f2bf(Fb[(quad * 8 + j) * 64 + pxme]);
#pragma unroll
        for (int mt = 0; mt < 16; ++mt) {
            short8 afrag = *(const short8*)(Wb + mt * 512 + lane * 8);
            acc[mt] = __builtin_amdgcn_mfma_f32_16x16x32_bf16(afrag, bfrag, acc[mt], 0, 0, 0);
        }
    }

    // Bias + per-pixel norm. C/D layout (validated): col(px)=lane&15, row(ch)=quad*4+r.
    float ss = 0.f;
#pragma unroll
    for (int mt = 0; mt < 16; ++mt) {
        float4_ bv = *(const float4_*)(bias + mt * 16 + quad * 4);
#pragma unroll
        for (int r = 0; r < 4; ++r) { float v = acc[mt][r] + bv[r]; acc[mt][r] = v; ss += v * v; }
    }
    ss += __shfl_xor(ss, 16);
    ss += __shfl_xor(ss, 32);
    const float inv = 1.f / sqrtf(fmaxf(ss, 1e-24f));

    __syncthreads();   // S buffers alias the K-loop buffers

    // Stage coarse unit vectors (32-B chunks per thread, coalesced).
    {   // u1: 16 px (2 rows x 8 cols): global row 2RB+lr, col 8CB+lc
        const int p1 = t >> 4, ck = (t & 15) * 16;
        const int lr = p1 >> 3, lc = p1 & 7;
        const short* src = u1 + ((size_t)(b * 1600 + (2 * RB + lr) * 40 + 8 * CB + lc)) * CCH + ck;
        *(short8*)(&S1[p1 * 256 + ck])     = *(const short8*)src;
        *(short8*)(&S1[p1 * 256 + ck + 8]) = *(const short8*)(src + 8);
    }
    if (t < 64) {   // u2: 4 px (1 row x 4 cols): row RB, col 4CB+p2
        const int p2 = t >> 4, ck = (t & 15) * 16;
        const short* src = u2 + ((size_t)(b * 400 + RB * 20 + 4 * CB + p2)) * CCH + ck;
        *(short8*)(&S2[p2 * 256 + ck])     = *(const short8*)src;
        *(short8*)(&S2[p2 * 256 + ck + 8]) = *(const short8*)(src + 8);
    }
    if (t < 32) {   // u3: 2 px (row RB>>1, cols 2CB..2CB+1)
        const int p3 = t >> 4, ck = (t & 15) * 16;
        const short* src = u3 + ((size_t)(b * 100 + (RB >> 1) * 10 + 2 * CB + p3)) * CCH + ck;
        *(short8*)(&S3[p3 * 256 + ck])     = *(const short8*)src;
        *(short8*)(&S3[p3 * 256 + ck + 8]) = *(const short8*)(src + 8);
    }
    __syncthreads();

    // Fine dots: px (pr,pc) = (pxme>>4, pxme&15); lane's 64 ch = mt*16 + quad*4 + r.
    const int pr = pxme >> 4, pc = pxme & 15;
    const int c1l = (pr >> 1) * 8 + (pc >> 1);
    const int c2l = pc >> 2;
    const int c3l = pc >> 3;
    float d01 = 0.f, d02 = 0.f, d03 = 0.f;
#pragma unroll
    for (int mt = 0; mt < 16; ++mt) {
        const int ch = mt * 16 + quad * 4;
        short4_ v1 = *(const short4_*)(&S1[c1l * 256 + ch]);
        short4_ v2 = *(const short4_*)(&S2[c2l * 256 + ch]);
        short4_ v3 = *(const short4_*)(&S3[c3l * 256 + ch]);
#pragma unroll
        for (int r = 0; r < 4; ++r) {
            float a = acc[mt][r] * inv;
            d01 += a * bf2f(v1[r]);
            d02 += a * bf2f(v2[r]);
            d03 += a * bf2f(v3[r]);
        }
    }
    {
        float vals[3] = {d01, d02, d03};
#pragma unroll
        for (int p = 0; p < 3; ++p) {
            float v = vals[p];
            v += __shfl_xor(v, 1);  v += __shfl_xor(v, 2);  v += __shfl_xor(v, 4);
            v += __shfl_xor(v, 8);  v += __shfl_xor(v, 16); v += __shfl_xor(v, 32);
            if (lane == 0) redF[wav * 3 + p] = v;
        }
    }

    // Coarse dots. Wave 0: d12/d13 per owned u1 px (16 px x 4 lanes, 64 ch per lane).
    if (wav == 0) {
        const int p1 = lane >> 2, q = lane & 3;
        const int lc = p1 & 7;
        const int par2 = lc >> 1;              // u2 local col
        const int par3 = lc >> 2;              // u3 local col
        float e12 = 0.f, e13 = 0.f;
#pragma unroll
        for (int k = 0; k < 16; ++k) {
            short4_ a1 = *(const short4_*)(&S1[p1 * 256 + q * 64 + k * 4]);
            short4_ a2 = *(const short4_*)(&S2[par2 * 256 + q * 64 + k * 4]);
            short4_ a3 = *(const short4_*)(&S3[par3 * 256 + q * 64 + k * 4]);
#pragma unroll
            for (int r = 0; r < 4; ++r) {
                float x1 = bf2f(a1[r]);
                e12 += x1 * bf2f(a2[r]);
                e13 += x1 * bf2f(a3[r]);
            }
        }
        float ev[2] = {e12, e13};
#pragma unroll
        for (int p = 0; p < 2; ++p) {
            float v = ev[p];
            v += __shfl_xor(v, 1);  v += __shfl_xor(v, 2);  v += __shfl_xor(v, 4);
            v += __shfl_xor(v, 8);  v += __shfl_xor(v, 16); v += __shfl_xor(v, 32);
            if (lane == 0) redC[p] = v;
        }
    } else if (wav == 1) {   // d23 per owned u2 px (4 px x 4 lanes)
        float e23 = 0.f;
        if (lane < 16) {
            const int p2 = lane >> 2, q = lane & 3;
            const int par3 = p2 >> 1;
#pragma unroll
            for (int k = 0; k < 16; ++k) {
                short4_ a2 = *(const short4_*)(&S2[p2 * 256 + q * 64 + k * 4]);
                short4_ a3 = *(const short4_*)(&S3[par3 * 256 + q * 64 + k * 4]);
#pragma unroll
                for (int r = 0; r < 4; ++r) e23 += bf2f(a2[r]) * bf2f(a3[r]);
            }
        }
        e23 += __shfl_xor(e23, 1);  e23 += __shfl_xor(e23, 2);  e23 += __shfl_xor(e23, 4);
        e23 += __shfl_xor(e23, 8);  e23 += __shfl_xor(e23, 16); e23 += __shfl_xor(e23, 32);
        if (lane == 0) redC[2] = e23;
    }
    __syncthreads();

    if (t < 6) {
        float v;
        if (t < 3) {
            v = redF[t] + redF[3 + t] + redF[6 + t] + redF[9 + t];
        } else v = redC[t - 3];
        partial[((size_t)b * 6 + t) * 100 + c] = v;
    }
}

// ---------- Softmax over j for each (b,i) row (sums 100 tile partials) ----------
__global__ void softmax4(const float* __restrict__ partial, float* __restrict__ out) {
    int t = threadIdx.x;
    if (t >= 128) return;
    int b = t >> 4, i = (t >> 2) & 3, j = t & 3;
    float a[4];
#pragma unroll
    for (int jj = 0; jj < 4; ++jj) {
        if (jj == i) { a[jj] = 1.0f; continue; }
        int lo = i < jj ? i : jj;
        int hi = i < jj ? jj : i;
        int pidx;
        if (lo == 0) pidx = hi - 1;          // (0,1)=0 (0,2)=1 (0,3)=2
        else if (lo == 1) pidx = 1 + hi;     // (1,2)=3 (1,3)=4
        else pidx = 5;                       // (2,3)=5
        const float* pp = partial + ((size_t)b * 6 + pidx) * 100;
        float s = 0.f;
        for (int k = 0; k < 100; ++k) s += pp[k];
        int rf = 80 >> lo;
        a[jj] = s / (float)(rf * rf);
    }
    float m = fmaxf(fmaxf(a[0], a[1]), fmaxf(a[2], a[3]));
    float e0 = expf(a[0] - m), e1 = expf(a[1] - m), e2 = expf(a[2] - m), e3 = expf(a[3] - m);
    float sum = e0 + e1 + e2 + e3;
    float ev = (j == 0) ? e0 : (j == 1) ? e1 : (j == 2) ? e2 : e3;
    out[t] = ev / sum;
}

extern "C" void kernel_launch(void* const* d_in, const int* in_sizes, int n_in,
                              void* d_out, int out_size, void* d_ws, size_t ws_size,
                              hipStream_t stream) {
    // setup_inputs dict insertion order: f0,w0,b0, f1,w1,b1, f2,w2,b2, f3,w3,b3
    const float* f[4]  = {(const float*)d_in[0], (const float*)d_in[3],
                          (const float*)d_in[6], (const float*)d_in[9]};
    const float* w[4]  = {(const float*)d_in[1], (const float*)d_in[4],
                          (const float*)d_in[7], (const float*)d_in[10]};
    const float* bs[4] = {(const float*)d_in[2], (const float*)d_in[5],
                          (const float*)d_in[8], (const float*)d_in[11]};

    char* ws = (char*)d_ws;
    size_t off = 0;
    short* u1 = (short*)(ws + off); off += (size_t)8 * CCH * 1600 * sizeof(short);
    short* u2 = (short*)(ws + off); off += (size_t)8 * CCH * 400  * sizeof(short);
    short* u3 = (short*)(ws + off); off += (size_t)8 * CCH * 100  * sizeof(short);
    short* wp = (short*)(ws + off); off += (size_t)65536 * sizeof(short);
    float* partial = (float*)(ws + off);   // 8*6*100 floats

    proj_small<<<304, 256, 0, stream>>>(f[1], f[2], f[3],
                                        w[0], w[1], w[2], w[3],
                                        bs[1], bs[2], bs[3],
                                        u1, u2, u3, wp);

    proj0_dots<<<dim3(100, 8), 256, 0, stream>>>(f[0], wp, bs[0],
                                                 u1, u2, u3, partial);

    softmax4<<<1, 128, 0, stream>>>(partial, (float*)d_out);
}